// Round 16
// baseline (478.511 us; speedup 1.0000x reference)
//
#include <hip/hip_runtime.h>
#include <math.h>

#define EPS 1e-5f

#define F_BIAS  1
#define F_DBN   2
#define F_GELU  4
#define F_RESID 8

typedef __attribute__((ext_vector_type(8))) __bf16 bf16x8;
typedef __attribute__((ext_vector_type(4))) float f32x4;
typedef __attribute__((ext_vector_type(8))) unsigned short u16x8;

__device__ __forceinline__ unsigned int pack2bf(float a, float b) {
    unsigned short ua = __builtin_bit_cast(unsigned short, (__bf16)a);
    unsigned short ub = __builtin_bit_cast(unsigned short, (__bf16)b);
    return (unsigned int)ua | ((unsigned int)ub << 16);
}

__device__ __forceinline__ void gload_lds16(const unsigned short* g, unsigned short* l) {
    __builtin_amdgcn_global_load_lds(
        (const __attribute__((address_space(1))) unsigned int*)g,
        (__attribute__((address_space(3))) unsigned int*)l,
        16, 0, 0);
}

// cheap tanh-gelu: u*sigmoid(2z)
__device__ __forceinline__ float gelu_f(float u) {
    float s = u * u;
    float w = u * fmaf(s, 0.0713548162726f, 1.59576912161f);
    float e = __expf(-w);
    return u * __builtin_amdgcn_rcpf(1.f + e);
}

// BK=32 (64B-row) conflict-free swizzle (PMC-verified R14: 4.7M -> 0).
#define SRC_SEG(lane)   ((((lane) & 3) ^ (((lane) >> 3) & 3)) * 8)
#define RD_SLOT(qc, hi) (((((qc) >> 1) ^ (hi)) & 3) * 8)

// path constants: ratios {2,4,8,16}
__device__ __constant__ int c_LKS[4]  = {1536, 768, 384, 192};
__device__ __constant__ int c_OFFB[4] = {0, 1572864, 2359296, 2752512};

// ---------------------------------------------------------------------------
// weights fp32 -> bf16
// ---------------------------------------------------------------------------
__global__ __launch_bounds__(256) void wcvt_kernel(
    const float* __restrict__ Wq, const float* __restrict__ Wk,
    const float* __restrict__ Wv, const float* __restrict__ Wo,
    const float* __restrict__ Wp, const float* __restrict__ W1,
    const float* __restrict__ W2, unsigned short* __restrict__ dst)
{
    const int WSZ = 65536;
    const int FSZ = 1048576;
    int i4 = blockIdx.x * blockDim.x + threadIdx.x;
    long long i = (long long)i4 * 4;
    const long long total = 5LL * WSZ + 2LL * FSZ;
    if (i >= total) return;
    #pragma unroll
    for (int j = 0; j < 4; ++j) {
        long long idx = i + j;
        float v;
        if      (idx < WSZ)            v = Wq[idx];
        else if (idx < 2 * WSZ)        v = Wk[idx - WSZ];
        else if (idx < 3 * WSZ)        v = Wv[idx - 2 * WSZ];
        else if (idx < 4 * WSZ)        v = Wo[idx - 3 * WSZ];
        else if (idx < 5 * WSZ)        v = Wp[idx - 4 * WSZ];
        else if (idx < 5 * WSZ + FSZ)  v = W1[idx - 5 * WSZ];
        else                           v = W2[idx - 5 * WSZ - FSZ];
        dst[idx] = __builtin_bit_cast(unsigned short, (__bf16)v);
    }
}

// ---------------------------------------------------------------------------
// hT = bf16(bn1(x))^T : x (N,C,L) f32 -> hT (N,L,C) bf16
// ---------------------------------------------------------------------------
__global__ __launch_bounds__(256) void bn_transpose_kernel(
    const float* __restrict__ x,
    const float* __restrict__ g, const float* __restrict__ b,
    const float* __restrict__ bm, const float* __restrict__ bvv,
    unsigned short* __restrict__ hT, int C, int L)
{
    __shared__ float ps[64][65];
    const int l0 = blockIdx.x * 64, ct = blockIdx.y, n = blockIdx.z;
    const int tid = threadIdx.x;
    const int c = tid >> 2, q = tid & 3;
    const int cg = ct * 64 + c;
    float inv = g[cg] * rsqrtf(bvv[cg] + EPS);
    float add = b[cg] - bm[cg] * inv;
    const float* xp = x + ((size_t)n * C + cg) * L + l0 + q * 16;
    #pragma unroll
    for (int s = 0; s < 4; ++s) {
        float4 vv = *(const float4*)&xp[s * 4];
        ps[c][q * 16 + s * 4 + 0] = fmaf(vv.x, inv, add);
        ps[c][q * 16 + s * 4 + 1] = fmaf(vv.y, inv, add);
        ps[c][q * 16 + s * 4 + 2] = fmaf(vv.z, inv, add);
        ps[c][q * 16 + s * 4 + 3] = fmaf(vv.w, inv, add);
    }
    __syncthreads();
    #pragma unroll
    for (int j = 0; j < 2; ++j) {
        int row = (tid >> 3) + 32 * j;
        int cc0 = (tid & 7) * 8;
        unsigned int w0 = pack2bf(ps[cc0 + 0][row], ps[cc0 + 1][row]);
        unsigned int w1 = pack2bf(ps[cc0 + 2][row], ps[cc0 + 3][row]);
        unsigned int w2 = pack2bf(ps[cc0 + 4][row], ps[cc0 + 5][row]);
        unsigned int w3 = pack2bf(ps[cc0 + 6][row], ps[cc0 + 7][row]);
        *(uint4*)&hT[((size_t)n * L + l0 + row) * C + ct * 64 + cc0] =
            make_uint4(w0, w1, w2, w3);
    }
}

// ---------------------------------------------------------------------------
// Pool+BN1 for ALL paths in one dispatch: grid (24, 2, N*4)
// ---------------------------------------------------------------------------
__global__ __launch_bounds__(256) void pool_bn_all_kernel(
    const float* __restrict__ x,
    const float* __restrict__ g, const float* __restrict__ b,
    const float* __restrict__ bm, const float* __restrict__ bvv,
    unsigned short* __restrict__ xa0T_all, int C, int L)
{
    const int p = blockIdx.z & 3;
    const int n = blockIdx.z >> 2;
    const int Lk = c_LKS[p];
    const int lk0 = blockIdx.x * 64;
    if (lk0 >= Lk) return;
    const int r = L / Lk;
    const int ct = blockIdx.y;
    __shared__ float ps[64][65];
    const int tid = threadIdx.x;
    const int c = tid >> 2, q = tid & 3;
    const int cg = p * 128 + ct * 64 + c;
    float inv = g[cg] * rsqrtf(bvv[cg] + EPS);
    float add = b[cg] - bm[cg] * inv;
    const float* xp = x + ((size_t)n * C + cg) * L;
    float rinv = 1.0f / (float)r;
    #pragma unroll
    for (int s = 0; s < 16; ++s) {
        int lk = q * 16 + s;
        const float* base = xp + (size_t)(lk0 + lk) * r;
        float sum = 0.f, mx = -INFINITY;
        for (int j = 0; j < r; j += 2) {
            float2 vv = *(const float2*)&base[j];
            float t0 = fmaf(vv.x, inv, add);
            float t1 = fmaf(vv.y, inv, add);
            sum += t0 + t1;
            mx = fmaxf(mx, fmaxf(t0, t1));
        }
        ps[c][lk] = sum * rinv + mx;
    }
    __syncthreads();
    unsigned short* dst = xa0T_all + c_OFFB[p];
    #pragma unroll
    for (int j = 0; j < 2; ++j) {
        int row = (tid >> 3) + 32 * j;
        int cc0 = (tid & 7) * 8;
        unsigned int w0 = pack2bf(ps[cc0 + 0][row], ps[cc0 + 1][row]);
        unsigned int w1 = pack2bf(ps[cc0 + 2][row], ps[cc0 + 3][row]);
        unsigned int w2 = pack2bf(ps[cc0 + 4][row], ps[cc0 + 5][row]);
        unsigned int w3 = pack2bf(ps[cc0 + 6][row], ps[cc0 + 7][row]);
        *(uint4*)&dst[((size_t)n * Lk + lk0 + row) * 128 + ct * 64 + cc0] =
            make_uint4(w0, w1, w2, w3);
    }
}

// ---------------------------------------------------------------------------
// bf16 MFMA GEMM 128x128, BK=32, counted-vmcnt 2-buffer pipeline,
// phase-conflict-free swizzle (SRC_SEG/RD_SLOT).
// ---------------------------------------------------------------------------
template<int OMODE>
__global__ __launch_bounds__(256) void gemm_bf(
    const unsigned short* __restrict__ A, const unsigned short* __restrict__ BT,
    int M, int K, int Npos, int ldBT, long long strideBT,
    const float* __restrict__ bias, float oscale, int flags,
    const float* __restrict__ g1, const float* __restrict__ b1p,
    const float* __restrict__ m1p, const float* __restrict__ v1p,
    const float* __restrict__ g2, const float* __restrict__ b2p,
    const float* __restrict__ m2p, const float* __restrict__ v2p,
    float* __restrict__ outN, long long strideN,
    const float* __restrict__ resid, long long strideR,
    unsigned short* __restrict__ outT, int ldT, int moff, long long strideT,
    int gKoff)
{
    __shared__ __align__(16) unsigned short As[2][128][32];
    __shared__ __align__(16) unsigned short Bs[2][128][32];

    const int tid = threadIdx.x;

    const int gdx = gridDim.x, gdy = gridDim.y;
    const int nwg = gdx * gdy * gridDim.z;
    int bid = blockIdx.x + gdx * (blockIdx.y + gdy * blockIdx.z);
    {
        int q = nwg >> 3, rr = nwg & 7;
        int xcd = bid & 7, idx = bid >> 3;
        bid = (xcd < rr ? xcd * (q + 1) : rr * (q + 1) + (xcd - rr) * q) + idx;
    }
    const int bx = bid % gdx;
    const int by = (bid / gdx) % gdy;
    const int bz = bid / (gdx * gdy);

    const int m0 = by * 128;
    const int p0 = bx * 128;
    const unsigned short* Bn = BT + (size_t)bz * strideBT
                              + (size_t)(m0 >> 7) * gKoff;

    const int wave = tid >> 6;
    const int lane = tid & 63;
    const int qcol = lane & 15;
    const int hi   = lane >> 4;
    const int wr   = wave >> 1;
    const int wc   = wave & 1;
    const int lrow = lane >> 2;
    const int sseg = SRC_SEG(lane);

    const unsigned short* aR0 = A + (size_t)(m0 + wave * 32 + lrow) * K + sseg;
    const unsigned short* aR1 = aR0 + (size_t)16 * K;
    int pr0 = p0 + wave * 32 + lrow;      if (pr0 > Npos - 1) pr0 = Npos - 1;
    int pr1 = p0 + wave * 32 + 16 + lrow; if (pr1 > Npos - 1) pr1 = Npos - 1;
    const unsigned short* bR0 = Bn + (size_t)pr0 * ldBT + sseg;
    const unsigned short* bR1 = Bn + (size_t)pr1 * ldBT + sseg;
    unsigned short* ldsA0 = &As[0][wave * 32][0];
    unsigned short* ldsA1 = &As[0][wave * 32 + 16][0];
    unsigned short* ldsB0 = &Bs[0][wave * 32][0];
    unsigned short* ldsB1 = &Bs[0][wave * 32 + 16][0];
    const int bufStride = 128 * 32;

    auto STAGE = [&](int b, int t) {
        const int ko = t * 32;
        gload_lds16(aR0 + ko, ldsA0 + b * bufStride);
        gload_lds16(aR1 + ko, ldsA1 + b * bufStride);
        gload_lds16(bR0 + ko, ldsB0 + b * bufStride);
        gload_lds16(bR1 + ko, ldsB1 + b * bufStride);
    };

    const int xr = RD_SLOT(qcol, hi);

    f32x4 acc[4][4] = {};
    const int nt = K >> 5;

    STAGE(0, 0);
    STAGE(1, 1);

    auto MFMA_STEP = [&](int b) {
        bf16x8 af[4], bfr[4];
        #pragma unroll
        for (int mi = 0; mi < 4; ++mi)
            af[mi] = *(const bf16x8*)&As[b][wr * 64 + mi * 16 + qcol][xr];
        #pragma unroll
        for (int ni = 0; ni < 4; ++ni)
            bfr[ni] = *(const bf16x8*)&Bs[b][wc * 64 + ni * 16 + qcol][xr];
        #pragma unroll
        for (int mi = 0; mi < 4; ++mi)
            #pragma unroll
            for (int ni = 0; ni < 4; ++ni)
                acc[mi][ni] = __builtin_amdgcn_mfma_f32_16x16x32_bf16(
                    af[mi], bfr[ni], acc[mi][ni], 0, 0, 0);
    };

    int cur = 0;
    for (int t = 0; t < nt - 1; ++t) {
        asm volatile("s_waitcnt vmcnt(4)" ::: "memory");
        __builtin_amdgcn_s_barrier();
        MFMA_STEP(cur);
        __builtin_amdgcn_s_barrier();
        if (t + 2 < nt) STAGE(cur, t + 2);
        cur ^= 1;
    }
    asm volatile("s_waitcnt vmcnt(0)" ::: "memory");
    __builtin_amdgcn_s_barrier();
    MFMA_STEP(cur);

    float* Cn = outN + (size_t)bz * strideN;
    const float* Rn = resid + (size_t)bz * strideR;
    unsigned short* Tn = outT + (size_t)bz * strideT;

    #pragma unroll
    for (int mi = 0; mi < 4; ++mi) {
        const int mb = m0 + wr * 64 + mi * 16 + hi * 4;
        float4 bv4 = make_float4(0.f, 0.f, 0.f, 0.f);
        if (flags & F_BIAS) bv4 = *(const float4*)&bias[mb];
        float s1[4], t1[4];
        if ((flags & F_DBN) || OMODE == 3) {
            float4 gg = *(const float4*)&g1[mb];
            float4 bb = *(const float4*)&b1p[mb];
            float4 mm = *(const float4*)&m1p[mb];
            float4 vv = *(const float4*)&v1p[mb];
            float gga[4] = {gg.x, gg.y, gg.z, gg.w};
            float bba[4] = {bb.x, bb.y, bb.z, bb.w};
            float mma[4] = {mm.x, mm.y, mm.z, mm.w};
            float vva[4] = {vv.x, vv.y, vv.z, vv.w};
            #pragma unroll
            for (int r2 = 0; r2 < 4; ++r2) {
                float iv = gga[r2] * rsqrtf(vva[r2] + EPS);
                s1[r2] = iv; t1[r2] = bba[r2] - mma[r2] * iv;
            }
        }
        float s2[4], t2[4];
        if (flags & F_DBN) {
            float4 gg = *(const float4*)&g2[mb];
            float4 bb = *(const float4*)&b2p[mb];
            float4 mm = *(const float4*)&m2p[mb];
            float4 vv = *(const float4*)&v2p[mb];
            float gga[4] = {gg.x, gg.y, gg.z, gg.w};
            float bba[4] = {bb.x, bb.y, bb.z, bb.w};
            float mma[4] = {mm.x, mm.y, mm.z, mm.w};
            float vva[4] = {vv.x, vv.y, vv.z, vv.w};
            #pragma unroll
            for (int r2 = 0; r2 < 4; ++r2) {
                float iv = gga[r2] * rsqrtf(vva[r2] + EPS);
                s2[r2] = iv; t2[r2] = bba[r2] - mma[r2] * iv;
            }
        }
        const float ba[4] = {bv4.x, bv4.y, bv4.z, bv4.w};
        #pragma unroll
        for (int ni = 0; ni < 4; ++ni) {
            const int cp = p0 + wc * 64 + ni * 16 + qcol;
            if (cp >= Npos) continue;
            float vals[4];
            #pragma unroll
            for (int r2 = 0; r2 < 4; ++r2) {
                float val = (acc[mi][ni][r2] + ba[r2]) * oscale;
                if (flags & F_DBN) {
                    val = fmaf(val, s1[r2], t1[r2]);
                    val = fmaf(val, s2[r2], t2[r2]);
                }
                if (flags & F_GELU) val = gelu_f(val);
                vals[r2] = val;
            }
            if (OMODE == 0 || OMODE == 3) {
                #pragma unroll
                for (int r2 = 0; r2 < 4; ++r2) {
                    size_t off = (size_t)(mb + r2) * Npos + cp;
                    float v = vals[r2];
                    if (flags & F_RESID) v += Rn[off];
                    Cn[off] = v;
                    vals[r2] = v;
                }
            }
            if (OMODE == 1) {
                *(uint2*)&Tn[(size_t)cp * ldT + moff + mb] =
                    make_uint2(pack2bf(vals[0], vals[1]), pack2bf(vals[2], vals[3]));
            }
            if (OMODE == 2) {
                #pragma unroll
                for (int r2 = 0; r2 < 4; ++r2)
                    Tn[(size_t)(mb + r2) * Npos + cp] =
                        __builtin_bit_cast(unsigned short, (__bf16)vals[r2]);
            }
            if (OMODE == 3) {
                float a0 = fmaf(vals[0], s1[0], t1[0]);
                float a1 = fmaf(vals[1], s1[1], t1[1]);
                float a2 = fmaf(vals[2], s1[2], t1[2]);
                float a3 = fmaf(vals[3], s1[3], t1[3]);
                *(uint2*)&Tn[(size_t)cp * ldT + moff + mb] =
                    make_uint2(pack2bf(a0, a1), pack2bf(a2, a3));
            }
        }
    }
}

// ---------------------------------------------------------------------------
// bf16 MFMA FFN GEMM: 128x256 tile, BK=32, 3-BUFFER counted-vmcnt ring
// (R15-proven: 2 blocks/CU, vmcnt(6) steady state, conflict-free swizzle).
// OMODE 1 adds an LDS-STAGED TRANSPOSE EPILOGUE: the 128x256 bf16 output
// tile is written to reused staging LDS as [cp][136] (272B rows: 16B-aligned,
// 2-way-bank writes = free) then streamed out as 256B-contiguous row
// segments -> full-line HBM writes (kills the 1.6x scatter amplification
// measured in R15: WRITE_SIZE 160MB vs 100MB ideal).
// OMODE: 0 = f32 natural out (+resid);  1 = bf16 transposed out [cp][ldT].
// ---------------------------------------------------------------------------
template<int OMODE, int FLAGS>
__global__ __launch_bounds__(512, 1) void gemm_ffn(
    const unsigned short* __restrict__ A, const unsigned short* __restrict__ BT,
    int K, int Npos, int ldBT, long long strideBT,
    const float* __restrict__ bias,
    float* __restrict__ outN, long long strideN,
    const float* __restrict__ resid, long long strideR,
    unsigned short* __restrict__ outT, int ldT, long long strideT)
{
    // unioned LDS: staging (3x128x32 + 3x256x32 u16 = 73728B) / epilogue [256][136]
    __shared__ __align__(16) unsigned short smem[3 * 128 * 32 + 3 * 256 * 32];
    typedef unsigned short (*AsT)[128][32];
    typedef unsigned short (*BsT)[256][32];
    AsT As = (AsT)smem;
    BsT Bs = (BsT)(smem + 3 * 128 * 32);

    const int tid = threadIdx.x;

    const int gdx = gridDim.x, gdy = gridDim.y;
    const int nwg = gdx * gdy * gridDim.z;
    int bid = blockIdx.x + gdx * (blockIdx.y + gdy * blockIdx.z);
    {
        int q = nwg >> 3, rr = nwg & 7;
        int xcd = bid & 7, idx = bid >> 3;
        bid = (xcd < rr ? xcd * (q + 1) : rr * (q + 1) + (xcd - rr) * q) + idx;
    }
    const int bx = bid % gdx;
    const int by = (bid / gdx) % gdy;
    const int bz = bid / (gdx * gdy);

    const int m0 = by * 128;
    const int p0 = bx * 256;
    const unsigned short* Bn = BT + (size_t)bz * strideBT;

    const int wave = tid >> 6;
    const int lane = tid & 63;
    const int qcol = lane & 15;
    const int hi   = lane >> 4;
    const int wr   = wave >> 2;      // 0..1 (M-half, 64 rows each)
    const int wc   = wave & 3;       // 0..3 (N-quarter, 64 cols)

    const int lrow4 = lane >> 2;
    const int sseg  = SRC_SEG(lane);

    const unsigned short* aS0 = A + (size_t)(m0 + wave * 16 + lrow4) * K + sseg;
    const unsigned short* bS0 = Bn + (size_t)(p0 + wave * 32 + lrow4) * ldBT + sseg;
    const unsigned short* bS1 = bS0 + (size_t)16 * ldBT;
    unsigned short* ldsA0 = &As[0][wave * 16][0];
    unsigned short* ldsB0 = &Bs[0][wave * 32][0];
    unsigned short* ldsB1 = &Bs[0][wave * 32 + 16][0];
    const int aStride = 128 * 32;
    const int bStride = 256 * 32;

    auto STAGE = [&](int b, int t) {   // 3 vm-ops per wave
        const int ko = t * 32;
        gload_lds16(aS0 + ko, ldsA0 + b * aStride);
        gload_lds16(bS0 + ko, ldsB0 + b * bStride);
        gload_lds16(bS1 + ko, ldsB1 + b * bStride);
    };

    const int xr = RD_SLOT(qcol, hi);

    f32x4 acc[4][4] = {};
    const int nt = K >> 5;

    STAGE(0, 0);
    STAGE(1, 1);
    STAGE(2, 2);

    auto MFMA_STEP = [&](int b) {
        bf16x8 af[4], bfr[4];
        #pragma unroll
        for (int mi = 0; mi < 4; ++mi)
            af[mi] = *(const bf16x8*)&As[b][wr * 64 + mi * 16 + qcol][xr];
        #pragma unroll
        for (int ni = 0; ni < 4; ++ni)
            bfr[ni] = *(const bf16x8*)&Bs[b][wc * 64 + ni * 16 + qcol][xr];
        #pragma unroll
        for (int mi = 0; mi < 4; ++mi)
            #pragma unroll
            for (int ni = 0; ni < 4; ++ni)
                acc[mi][ni] = __builtin_amdgcn_mfma_f32_16x16x32_bf16(
                    af[mi], bfr[ni], acc[mi][ni], 0, 0, 0);
    };

    int cur = 0;
    for (int t = 0; t < nt; ++t) {
        const int rem = nt - t;
        if (rem >= 3)      { asm volatile("s_waitcnt vmcnt(6)" ::: "memory"); }
        else if (rem == 2) { asm volatile("s_waitcnt vmcnt(3)" ::: "memory"); }
        else               { asm volatile("s_waitcnt vmcnt(0)" ::: "memory"); }
        __builtin_amdgcn_s_barrier();
        __builtin_amdgcn_s_setprio(1);
        MFMA_STEP(cur);
        __builtin_amdgcn_s_setprio(0);
        __builtin_amdgcn_s_barrier();
        if (t + 3 < nt) STAGE(cur, t + 3);
        cur = (cur == 2) ? 0 : cur + 1;
    }

    float* Cn = outN + (size_t)bz * strideN;
    const float* Rn = resid + (size_t)bz * strideR;
    unsigned short* Tn = outT + (size_t)bz * strideT;

    if (OMODE == 1) {
        // ---- LDS-staged transpose epilogue (coalesced global writes) ----
        __syncthreads();    // all MFMA LDS reads done; pipeline fully drained
        #pragma unroll
        for (int mi = 0; mi < 4; ++mi) {
            const int mbl = wr * 64 + mi * 16 + hi * 4;   // 0..127
            const int mbg = m0 + mbl;
            float ba[4] = {0.f, 0.f, 0.f, 0.f};
            if (FLAGS & F_BIAS) {
                float4 bv4 = *(const float4*)&bias[mbg];
                ba[0] = bv4.x; ba[1] = bv4.y; ba[2] = bv4.z; ba[3] = bv4.w;
            }
            #pragma unroll
            for (int ni = 0; ni < 4; ++ni) {
                const int cpl = wc * 64 + ni * 16 + qcol;  // 0..255
                float vals[4];
                #pragma unroll
                for (int r2 = 0; r2 < 4; ++r2) {
                    float val = acc[mi][ni][r2] + ba[r2];
                    if (FLAGS & F_GELU) val = gelu_f(val);
                    vals[r2] = val;
                }
                *(uint2*)&smem[cpl * 136 + mbl] =
                    make_uint2(pack2bf(vals[0], vals[1]), pack2bf(vals[2], vals[3]));
            }
        }
        __syncthreads();
        // stream out: 256 rows x 256B, 16 lanes x 16B contiguous per row
        #pragma unroll
        for (int pass = 0; pass < 8; ++pass) {
            const int row = pass * 32 + (tid >> 4);
            const int c16 = (tid & 15) * 8;
            uint4 v = *(const uint4*)&smem[row * 136 + c16];
            *(uint4*)&Tn[(size_t)(p0 + row) * ldT + m0 + c16] = v;
        }
    } else {
        #pragma unroll
        for (int mi = 0; mi < 4; ++mi) {
            const int mb = m0 + wr * 64 + mi * 16 + hi * 4;
            float ba[4] = {0.f, 0.f, 0.f, 0.f};
            if (FLAGS & F_BIAS) {
                float4 bv4 = *(const float4*)&bias[mb];
                ba[0] = bv4.x; ba[1] = bv4.y; ba[2] = bv4.z; ba[3] = bv4.w;
            }
            #pragma unroll
            for (int ni = 0; ni < 4; ++ni) {
                const int cp = p0 + wc * 64 + ni * 16 + qcol;
                float vals[4];
                #pragma unroll
                for (int r2 = 0; r2 < 4; ++r2) {
                    float val = acc[mi][ni][r2] + ba[r2];
                    if (FLAGS & F_GELU) val = gelu_f(val);
                    vals[r2] = val;
                }
                #pragma unroll
                for (int r2 = 0; r2 < 4; ++r2) {
                    size_t off = (size_t)(mb + r2) * Npos + cp;
                    float v = vals[r2];
                    if (FLAGS & F_RESID) v += Rn[off];
                    Cn[off] = v;
                }
            }
        }
    }
}

// ---------------------------------------------------------------------------
// Grouped per-path GEMM (K=128, M=128 per path), all 4 paths in one dispatch.
// ---------------------------------------------------------------------------
template<int MODE>
__global__ __launch_bounds__(256) void gemm_path(
    const unsigned short* __restrict__ A0, const unsigned short* __restrict__ A1,
    const unsigned short* __restrict__ Bsrc,
    const float* __restrict__ bias0, const float* __restrict__ bias1,
    const float* __restrict__ agg, const float* __restrict__ agb,
    const float* __restrict__ agm, const float* __restrict__ agv,
    const float* __restrict__ ang, const float* __restrict__ anb,
    const float* __restrict__ anm, const float* __restrict__ anv,
    unsigned short* __restrict__ out0, unsigned short* __restrict__ out1)
{
    __shared__ __align__(16) unsigned short As[2][128][32];
    __shared__ __align__(16) unsigned short Bs[2][128][32];

    const int tid = threadIdx.x;
    const int gdx = gridDim.x, gdy = gridDim.y;
    const int nwg = gdx * gdy * gridDim.z;
    int bid = blockIdx.x + gdx * (blockIdx.y + gdy * blockIdx.z);
    {
        int q = nwg >> 3, rr = nwg & 7;
        int xcd = bid & 7, idx = bid >> 3;
        bid = (xcd < rr ? xcd * (q + 1) : rr * (q + 1) + (xcd - rr) * q) + idx;
    }
    const int bx = bid % gdx;
    const int by = (bid / gdx) % gdy;
    const int bz = bid / (gdx * gdy);

    int p, px;
    if      (bx < 12) { p = 0; px = bx; }
    else if (bx < 18) { p = 1; px = bx - 12; }
    else if (bx < 21) { p = 2; px = bx - 18; }
    else              { p = 3; px = bx - 21; }
    const int Lk = c_LKS[p];
    const int offb = c_OFFB[p];
    const int c0 = p * 128;
    const int p0 = px * 128;
    const int K = 128;

    const unsigned short* A = (MODE == 1 && by == 1 ? A1 : A0) + p * 16384;
    const unsigned short* Bn = Bsrc + offb + (size_t)bz * Lk * 128;

    const int wave = tid >> 6;
    const int lane = tid & 63;
    const int qcol = lane & 15;
    const int hi   = lane >> 4;
    const int wr   = wave >> 1;
    const int wc   = wave & 1;
    const int lrow = lane >> 2;
    const int sseg = SRC_SEG(lane);

    const unsigned short* aR0 = A + (size_t)(wave * 32 + lrow) * K + sseg;
    const unsigned short* aR1 = aR0 + (size_t)16 * K;
    int pr0 = p0 + wave * 32 + lrow;      if (pr0 > Lk - 1) pr0 = Lk - 1;
    int pr1 = p0 + wave * 32 + 16 + lrow; if (pr1 > Lk - 1) pr1 = Lk - 1;
    const unsigned short* bR0 = Bn + (size_t)pr0 * 128 + sseg;
    const unsigned short* bR1 = Bn + (size_t)pr1 * 128 + sseg;
    unsigned short* ldsA0 = &As[0][wave * 32][0];
    unsigned short* ldsA1 = &As[0][wave * 32 + 16][0];
    unsigned short* ldsB0 = &Bs[0][wave * 32][0];
    unsigned short* ldsB1 = &Bs[0][wave * 32 + 16][0];
    const int bufStride = 128 * 32;

    auto STAGE = [&](int b, int t) {
        const int ko = t * 32;
        gload_lds16(aR0 + ko, ldsA0 + b * bufStride);
        gload_lds16(aR1 + ko, ldsA1 + b * bufStride);
        gload_lds16(bR0 + ko, ldsB0 + b * bufStride);
        gload_lds16(bR1 + ko, ldsB1 + b * bufStride);
    };

    const int xr = RD_SLOT(qcol, hi);

    f32x4 acc[4][4] = {};
    STAGE(0, 0);
    STAGE(1, 1);

    auto MFMA_STEP = [&](int b) {
        bf16x8 af[4], bfr[4];
        #pragma unroll
        for (int mi = 0; mi < 4; ++mi)
            af[mi] = *(const bf16x8*)&As[b][wr * 64 + mi * 16 + qcol][xr];
        #pragma unroll
        for (int ni = 0; ni < 4; ++ni)
            bfr[ni] = *(const bf16x8*)&Bs[b][wc * 64 + ni * 16 + qcol][xr];
        #pragma unroll
        for (int mi = 0; mi < 4; ++mi)
            #pragma unroll
            for (int ni = 0; ni < 4; ++ni)
                acc[mi][ni] = __builtin_amdgcn_mfma_f32_16x16x32_bf16(
                    af[mi], bfr[ni], acc[mi][ni], 0, 0, 0);
    };

    int cur = 0;
    const int nt = 4;
    for (int t = 0; t < nt - 1; ++t) {
        asm volatile("s_waitcnt vmcnt(4)" ::: "memory");
        __builtin_amdgcn_s_barrier();
        MFMA_STEP(cur);
        __builtin_amdgcn_s_barrier();
        if (t + 2 < nt) STAGE(cur, t + 2);
        cur ^= 1;
    }
    asm volatile("s_waitcnt vmcnt(0)" ::: "memory");
    __builtin_amdgcn_s_barrier();
    MFMA_STEP(cur);

    const bool isV = (MODE == 1 && by == 1);
    unsigned short* Tn = (isV ? out1 : out0) + offb + (size_t)bz * Lk * 128;
    const float* bias = (MODE == 0) ? nullptr : (by == 0 ? bias0 : bias1);

    #pragma unroll
    for (int mi = 0; mi < 4; ++mi) {
        const int mb = wr * 64 + mi * 16 + hi * 4;
        float ba[4] = {0.f, 0.f, 0.f, 0.f};
        if (MODE == 1) {
            float4 bv4 = *(const float4*)&bias[c0 + mb];
            ba[0] = bv4.x; ba[1] = bv4.y; ba[2] = bv4.z; ba[3] = bv4.w;
        }
        float s1[4], t1[4], s2[4], t2[4];
        if (MODE == 0) {
            #pragma unroll
            for (int r2 = 0; r2 < 4; ++r2) {
                int gm = c0 + mb + r2;
                float i1 = agg[gm] * rsqrtf(agv[gm] + EPS);
                s1[r2] = i1; t1[r2] = agb[gm] - agm[gm] * i1;
                float i2 = ang[gm] * rsqrtf(anv[gm] + EPS);
                s2[r2] = i2; t2[r2] = anb[gm] - anm[gm] * i2;
            }
        }
        #pragma unroll
        for (int ni = 0; ni < 4; ++ni) {
            const int cp = p0 + wc * 64 + ni * 16 + qcol;
            if (cp >= Lk) continue;
            float vals[4];
            #pragma unroll
            for (int r2 = 0; r2 < 4; ++r2) {
                float val = acc[mi][ni][r2] + ba[r2];
                if (MODE == 0) {
                    val = fmaf(val, s1[r2], t1[r2]);
                    val = fmaf(val, s2[r2], t2[r2]);
                }
                vals[r2] = val;
            }
            if (!isV) {
                *(uint2*)&Tn[(size_t)cp * 128 + mb] =
                    make_uint2(pack2bf(vals[0], vals[1]), pack2bf(vals[2], vals[3]));
            } else {
                #pragma unroll
                for (int r2 = 0; r2 < 4; ++r2)
                    Tn[(size_t)(mb + r2) * Lk + cp] =
                        __builtin_bit_cast(unsigned short, (__bf16)vals[r2]);
            }
        }
    }
}

// ---------------------------------------------------------------------------
// Flash attention, all paths; K/V staged in block-shared LDS (counted-vmcnt
// 2-buffer pipeline, 128B-row XOR swizzle). grid (48, N*2, 4).
// ---------------------------------------------------------------------------
__global__ __launch_bounds__(256) void attn_bf_all_kernel(
    const unsigned short* __restrict__ qT, const unsigned short* __restrict__ kT_all,
    const unsigned short* __restrict__ vN_all, unsigned short* __restrict__ obT,
    int L)
{
    const int p = blockIdx.z;
    const int Lk = c_LKS[p];
    const int offb = c_OFFB[p];
    const int l0 = blockIdx.x * 64;
    const int nh = blockIdx.y;
    const int n = nh >> 1, h = nh & 1;
    const unsigned short* qn = qT + (size_t)n * L * 512 + p * 128 + h * 64;
    const unsigned short* kn = kT_all + offb + (size_t)n * Lk * 128 + h * 64;
    const unsigned short* vn = vN_all + offb + ((size_t)n * 128 + h * 64) * Lk;
    unsigned short*       on = obT + (size_t)n * L * 512 + p * 128 + h * 64;

    __shared__ __align__(16) unsigned short Ks[2][64][64];
    __shared__ __align__(16) unsigned short Vs[2][64][64];
    __shared__ __align__(16) unsigned short Ps[4][16][72];

    const int tid = threadIdx.x;
    const int wave = tid >> 6;
    const int lane = tid & 63;
    const int qcol = lane & 15;
    const int hi   = lane >> 4;
    const int ql   = wave * 16 + qcol;

    const int srow = lane >> 3;
    const int sxor = (lane & 7) ^ srow;
    const unsigned short* kS0 = kn + (size_t)(wave * 16 + srow) * 128 + sxor * 8;
    const unsigned short* kS1 = kn + (size_t)(wave * 16 + 8 + srow) * 128 + sxor * 8;
    const unsigned short* vS0 = vn + (size_t)(wave * 16 + srow) * Lk + sxor * 8;
    const unsigned short* vS1 = vn + (size_t)(wave * 16 + 8 + srow) * Lk + sxor * 8;
    unsigned short* ldsK0 = &Ks[0][wave * 16][0];
    unsigned short* ldsK1 = &Ks[0][wave * 16 + 8][0];
    unsigned short* ldsV0 = &Vs[0][wave * 16][0];
    unsigned short* ldsV1 = &Vs[0][wave * 16 + 8][0];
    const int bufStride = 64 * 64;

    auto STAGE = [&](int b, int t) {
        const int mc = t * 64;
        gload_lds16(kS0 + (size_t)mc * 128, ldsK0 + b * bufStride);
        gload_lds16(kS1 + (size_t)mc * 128, ldsK1 + b * bufStride);
        gload_lds16(vS0 + mc, ldsV0 + b * bufStride);
        gload_lds16(vS1 + mc, ldsV1 + b * bufStride);
    };

    const int x0 = (hi ^ (qcol & 7)) * 8;
    const int x1 = x0 ^ 32;

    bf16x8 qf0 = *(const bf16x8*)&qn[(size_t)(l0 + ql) * 512 + hi * 8];
    bf16x8 qf1 = *(const bf16x8*)&qn[(size_t)(l0 + ql) * 512 + 32 + hi * 8];

    f32x4 o_acc[4] = {};
    float mrow = -INFINITY, lrow = 0.f;
    const int nt = Lk >> 6;

    STAGE(0, 0);
    STAGE(1, 1);

    auto COMPUTE = [&](int b) {
        f32x4 sacc[4];
        #pragma unroll
        for (int kt = 0; kt < 4; ++kt) {
            bf16x8 k0 = *(const bf16x8*)&Ks[b][kt * 16 + qcol][x0];
            bf16x8 k1 = *(const bf16x8*)&Ks[b][kt * 16 + qcol][x1];
            f32x4 a = {};
            a = __builtin_amdgcn_mfma_f32_16x16x32_bf16(k0, qf0, a, 0, 0, 0);
            a = __builtin_amdgcn_mfma_f32_16x16x32_bf16(k1, qf1, a, 0, 0, 0);
            sacc[kt] = a;
        }
        float m0 = fmaxf(fmaxf(sacc[0][0], sacc[0][1]), fmaxf(sacc[0][2], sacc[0][3]));
        float m1 = fmaxf(fmaxf(sacc[1][0], sacc[1][1]), fmaxf(sacc[1][2], sacc[1][3]));
        float m2 = fmaxf(fmaxf(sacc[2][0], sacc[2][1]), fmaxf(sacc[2][2], sacc[2][3]));
        float m3 = fmaxf(fmaxf(sacc[3][0], sacc[3][1]), fmaxf(sacc[3][2], sacc[3][3]));
        float cm = fmaxf(fmaxf(m0, m1), fmaxf(m2, m3));
        cm = fmaxf(cm, __shfl_xor(cm, 16));
        cm = fmaxf(cm, __shfl_xor(cm, 32));
        float nm = fmaxf(mrow, cm);
        float alpha = __expf(mrow - nm);
        float csum = 0.f;
        unsigned int pw[4][2];
        #pragma unroll
        for (int kt = 0; kt < 4; ++kt) {
            float p0 = __expf(sacc[kt][0] - nm);
            float p1 = __expf(sacc[kt][1] - nm);
            float p2 = __expf(sacc[kt][2] - nm);
            float p3 = __expf(sacc[kt][3] - nm);
            csum += (p0 + p1) + (p2 + p3);
            pw[kt][0] = pack2bf(p0, p1);
            pw[kt][1] = pack2bf(p2, p3);
        }
        csum += __shfl_xor(csum, 16);
        csum += __shfl_xor(csum, 32);
        lrow = lrow * alpha + csum;
        mrow = nm;

        #pragma unroll
        for (int kt = 0; kt < 4; ++kt)
            *(uint2*)&Ps[wave][qcol][kt * 16 + hi * 4] =
                make_uint2(pw[kt][0], pw[kt][1]);

        #pragma unroll
        for (int et = 0; et < 4; ++et)
            #pragma unroll
            for (int r2 = 0; r2 < 4; ++r2) o_acc[et][r2] *= alpha;

        bf16x8 pf0 = *(const bf16x8*)&Ps[wave][qcol][hi * 8];
        bf16x8 pf1 = *(const bf16x8*)&Ps[wave][qcol][hi * 8 + 32];
        #pragma unroll
        for (int et = 0; et < 4; ++et) {
            bf16x8 v0 = *(const bf16x8*)&Vs[b][et * 16 + qcol][x0];
            bf16x8 v1 = *(const bf16x8*)&Vs[b][et * 16 + qcol][x1];
            o_acc[et] = __builtin_amdgcn_mfma_f32_16x16x32_bf16(v0, pf0, o_acc[et], 0, 0, 0);
            o_acc[et] = __builtin_amdgcn_mfma_f32_16x16x32_bf16(v1, pf1, o_acc[et], 0, 0, 0);
        }
    };

    int cur = 0;
    for (int t = 0; t < nt - 1; ++t) {
        asm volatile("s_waitcnt vmcnt(4)" ::: "memory");
        __builtin_amdgcn_s_barrier();
        COMPUTE(cur);
        __builtin_amdgcn_s_barrier();
        if (t + 2 < nt) STAGE(cur, t + 2);
        cur ^= 1;
    }
    asm volatile("s_waitcnt vmcnt(0)" ::: "memory");
    __builtin_amdgcn_s_barrier();
    COMPUTE(cur);

    float invl = 1.f / lrow;
    #pragma unroll
    for (int et = 0; et < 4; ++et) {
        float a0 = o_acc[et][0] * invl, a1 = o_acc[et][1] * invl;
        float a2 = o_acc[et][2] * invl, a3 = o_acc[et][3] * invl;
        *(uint2*)&on[(size_t)(l0 + ql) * 512 + et * 16 + hi * 4] =
            make_uint2(pack2bf(a0, a1), pack2bf(a2, a3));
    }
}

// ---------------------------------------------------------------------------
extern "C" void kernel_launch(void* const* d_in, const int* in_sizes, int n_in,
                              void* d_out, int out_size, void* d_ws, size_t ws_size,
                              hipStream_t stream)
{
    const float* x   = (const float*)d_in[0];
    const float* n1g = (const float*)d_in[1];
    const float* n1b = (const float*)d_in[2];
    const float* n1m = (const float*)d_in[3];
    const float* n1v = (const float*)d_in[4];
    const float* n2g = (const float*)d_in[5];
    const float* n2b = (const float*)d_in[6];
    const float* n2m = (const float*)d_in[7];
    const float* n2v = (const float*)d_in[8];
    const float* Wq  = (const float*)d_in[9];
    const float* Wk  = (const float*)d_in[10];
    const float* Wv  = (const float*)d_in[11];
    const float* Wo  = (const float*)d_in[12];
    const float* Wp  = (const float*)d_in[13];
    const float* bq  = (const float*)d_in[14];
    const float* bk  = (const float*)d_in[15];
    const float* bv  = (const float*)d_in[16];
    const float* bo  = (const float*)d_in[17];
    const float* agg = (const float*)d_in[18];
    const float* agb = (const float*)d_in[19];
    const float* agm = (const float*)d_in[20];
    const float* agv = (const float*)d_in[21];
    const float* ang = (const float*)d_in[22];
    const float* anb = (const float*)d_in[23];
    const float* anm = (const float*)d_in[24];
    const float* anv = (const float*)d_in[25];
    const float* W1  = (const float*)d_in[26];
    const float* b1  = (const float*)d_in[27];
    const float* W2  = (const float*)d_in[28];
    const float* b2  = (const float*)d_in[29];

    float* out = (float*)d_out;
    unsigned short* wsb = (unsigned short*)d_ws;

    const int N = 8, Cc = 512, L = 3072, FF = 2048;
    const int WSZ = 65536, FSZ = 1048576;
    const size_t PATHBUF = 2949120;

    unsigned short* wbf      = wsb;
    unsigned short* hT       = wbf      + 5 * WSZ + 2 * FSZ;
    unsigned short* h2T      = hT;                              // alias
    unsigned short* obT      = hT       + (size_t)N * L * Cc;
    unsigned short* xa0T_all = obT      + (size_t)N * L * 512;
    unsigned short* xabT_all = xa0T_all + PATHBUF;
    unsigned short* kT_all   = xabT_all + PATHBUF;
    unsigned short* vN_all   = kT_all   + PATHBUF;
    unsigned short* m1T      = vN_all   + PATHBUF;
    unsigned short* qTall    = m1T;

    const unsigned short* WqB = wbf;
    const unsigned short* WkB = wbf + WSZ;
    const unsigned short* WvB = wbf + 2 * WSZ;
    const unsigned short* WoB = wbf + 3 * WSZ;
    const unsigned short* WpB = wbf + 4 * WSZ;
    const unsigned short* W1B = wbf + 5 * WSZ;
    const unsigned short* W2B = wbf + 5 * WSZ + FSZ;

    const float* nul = nullptr;
    float* nulf = nullptr;
    unsigned short* nulu = nullptr;

    {
        long long tot4 = (5LL * WSZ + 2LL * FSZ) / 4;
        wcvt_kernel<<<dim3((unsigned)((tot4 + 255) / 256)), dim3(256), 0, stream>>>(
            Wq, Wk, Wv, Wo, Wp, W1, W2, wbf);
    }
    bn_transpose_kernel<<<dim3(L / 64, Cc / 64, N), dim3(256), 0, stream>>>(
        x, n1g, n1b, n1m, n1v, hT, Cc, L);

    pool_bn_all_kernel<<<dim3(24, 2, N * 4), dim3(256), 0, stream>>>(
        x, n1g, n1b, n1m, n1v, xa0T_all, Cc, L);

    // grouped Q: all paths, block-diag Wq (128^2 kernel, K=128)
    gemm_bf<1><<<dim3(L / 128, 4, N), dim3(256), 0, stream>>>(
        WqB, hT, 512, 128, L, Cc, (long long)L * Cc,
        bq, 0.125f, F_BIAS,
        nul, nul, nul, nul, nul, nul, nul, nul,
        nulf, 0, nul, 0, qTall, 512, 0, (long long)L * 512, 128);

    // grouped Wp (all paths)
    gemm_path<0><<<dim3(23, 1, N), dim3(256), 0, stream>>>(
        WpB, nulu, xa0T_all, nul, nul,
        agg, agb, agm, agv, ang, anb, anm, anv,
        xabT_all, nulu);

    // grouped Wk+Wv (all paths)
    gemm_path<1><<<dim3(23, 2, N), dim3(256), 0, stream>>>(
        WkB, WvB, xabT_all, bk, bv,
        nul, nul, nul, nul, nul, nul, nul, nul,
        kT_all, vN_all);

    // all-path attention
    attn_bf_all_kernel<<<dim3(L / 64, N * 2, 4), dim3(256), 0, stream>>>(
        qTall, kT_all, vN_all, obT, L);

    // grouped Wo: out = x + Wo @ o + bo (f32), h2T aux = bf16(bn2(out))
    gemm_bf<3><<<dim3(L / 128, 4, N), dim3(256), 0, stream>>>(
        WoB, obT, 512, 128, L, 512, (long long)L * 512,
        bo, 1.f, F_BIAS | F_RESID,
        n2g, n2b, n2m, n2v,
        nul, nul, nul, nul,
        out, (long long)Cc * L,
        x, (long long)Cc * L,
        h2T, Cc, 0, (long long)L * Cc, 128);

    // FFN: both on 128x256 / 3-buffer deep pipeline (2 blocks/CU)
    // m1T = bf16(gelu(W1 @ h2 + b1))^T   (LDS-transposed coalesced epilogue)
    gemm_ffn<1, F_BIAS | F_GELU><<<dim3(L / 256, FF / 128, N), dim3(512), 0, stream>>>(
        W1B, h2T, Cc, L, Cc, (long long)L * Cc,
        b1,
        nulf, 0, nul, 0,
        m1T, FF, (long long)L * FF);

    // out += W2 @ m1 + b2
    gemm_ffn<0, F_BIAS | F_RESID><<<dim3(L / 256, Cc / 128, N), dim3(512), 0, stream>>>(
        W2B, m1T, FF, L, FF, (long long)L * FF,
        b2,
        out, (long long)Cc * L, out, (long long)Cc * L,
        nulu, 0, 0);
}

// Round 17
// 451.784 us; speedup vs baseline: 1.0592x; 1.0592x over previous
//
#include <hip/hip_runtime.h>
#include <math.h>

#define EPS 1e-5f

#define F_BIAS  1
#define F_DBN   2
#define F_GELU  4
#define F_RESID 8

typedef __attribute__((ext_vector_type(8))) __bf16 bf16x8;
typedef __attribute__((ext_vector_type(4))) float f32x4;
typedef __attribute__((ext_vector_type(8))) unsigned short u16x8;

__device__ __forceinline__ unsigned int pack2bf(float a, float b) {
    unsigned short ua = __builtin_bit_cast(unsigned short, (__bf16)a);
    unsigned short ub = __builtin_bit_cast(unsigned short, (__bf16)b);
    return (unsigned int)ua | ((unsigned int)ub << 16);
}

__device__ __forceinline__ void gload_lds16(const unsigned short* g, unsigned short* l) {
    __builtin_amdgcn_global_load_lds(
        (const __attribute__((address_space(1))) unsigned int*)g,
        (__attribute__((address_space(3))) unsigned int*)l,
        16, 0, 0);
}

// cheap tanh-gelu: u*sigmoid(2z)
__device__ __forceinline__ float gelu_f(float u) {
    float s = u * u;
    float w = u * fmaf(s, 0.0713548162726f, 1.59576912161f);
    float e = __expf(-w);
    return u * __builtin_amdgcn_rcpf(1.f + e);
}

// BK=32 (64B-row) conflict-free swizzle (PMC-verified R14: 4.7M -> 0).
#define SRC_SEG(lane)   ((((lane) & 3) ^ (((lane) >> 3) & 3)) * 8)
#define RD_SLOT(qc, hi) (((((qc) >> 1) ^ (hi)) & 3) * 8)

// path constants: ratios {2,4,8,16}
__device__ __constant__ int c_LKS[4]  = {1536, 768, 384, 192};
__device__ __constant__ int c_OFFB[4] = {0, 1572864, 2359296, 2752512};

// ---------------------------------------------------------------------------
// weights fp32 -> bf16
// ---------------------------------------------------------------------------
__global__ __launch_bounds__(256) void wcvt_kernel(
    const float* __restrict__ Wq, const float* __restrict__ Wk,
    const float* __restrict__ Wv, const float* __restrict__ Wo,
    const float* __restrict__ Wp, const float* __restrict__ W1,
    const float* __restrict__ W2, unsigned short* __restrict__ dst)
{
    const int WSZ = 65536;
    const int FSZ = 1048576;
    int i4 = blockIdx.x * blockDim.x + threadIdx.x;
    long long i = (long long)i4 * 4;
    const long long total = 5LL * WSZ + 2LL * FSZ;
    if (i >= total) return;
    #pragma unroll
    for (int j = 0; j < 4; ++j) {
        long long idx = i + j;
        float v;
        if      (idx < WSZ)            v = Wq[idx];
        else if (idx < 2 * WSZ)        v = Wk[idx - WSZ];
        else if (idx < 3 * WSZ)        v = Wv[idx - 2 * WSZ];
        else if (idx < 4 * WSZ)        v = Wo[idx - 3 * WSZ];
        else if (idx < 5 * WSZ)        v = Wp[idx - 4 * WSZ];
        else if (idx < 5 * WSZ + FSZ)  v = W1[idx - 5 * WSZ];
        else                           v = W2[idx - 5 * WSZ - FSZ];
        dst[idx] = __builtin_bit_cast(unsigned short, (__bf16)v);
    }
}

// ---------------------------------------------------------------------------
// hT = bf16(bn1(x))^T : x (N,C,L) f32 -> hT (N,L,C) bf16
// ---------------------------------------------------------------------------
__global__ __launch_bounds__(256) void bn_transpose_kernel(
    const float* __restrict__ x,
    const float* __restrict__ g, const float* __restrict__ b,
    const float* __restrict__ bm, const float* __restrict__ bvv,
    unsigned short* __restrict__ hT, int C, int L)
{
    __shared__ float ps[64][65];
    const int l0 = blockIdx.x * 64, ct = blockIdx.y, n = blockIdx.z;
    const int tid = threadIdx.x;
    const int c = tid >> 2, q = tid & 3;
    const int cg = ct * 64 + c;
    float inv = g[cg] * rsqrtf(bvv[cg] + EPS);
    float add = b[cg] - bm[cg] * inv;
    const float* xp = x + ((size_t)n * C + cg) * L + l0 + q * 16;
    #pragma unroll
    for (int s = 0; s < 4; ++s) {
        float4 vv = *(const float4*)&xp[s * 4];
        ps[c][q * 16 + s * 4 + 0] = fmaf(vv.x, inv, add);
        ps[c][q * 16 + s * 4 + 1] = fmaf(vv.y, inv, add);
        ps[c][q * 16 + s * 4 + 2] = fmaf(vv.z, inv, add);
        ps[c][q * 16 + s * 4 + 3] = fmaf(vv.w, inv, add);
    }
    __syncthreads();
    #pragma unroll
    for (int j = 0; j < 2; ++j) {
        int row = (tid >> 3) + 32 * j;
        int cc0 = (tid & 7) * 8;
        unsigned int w0 = pack2bf(ps[cc0 + 0][row], ps[cc0 + 1][row]);
        unsigned int w1 = pack2bf(ps[cc0 + 2][row], ps[cc0 + 3][row]);
        unsigned int w2 = pack2bf(ps[cc0 + 4][row], ps[cc0 + 5][row]);
        unsigned int w3 = pack2bf(ps[cc0 + 6][row], ps[cc0 + 7][row]);
        *(uint4*)&hT[((size_t)n * L + l0 + row) * C + ct * 64 + cc0] =
            make_uint4(w0, w1, w2, w3);
    }
}

// ---------------------------------------------------------------------------
// Pool+BN1 for ALL paths in one dispatch: grid (24, 2, N*4)
// ---------------------------------------------------------------------------
__global__ __launch_bounds__(256) void pool_bn_all_kernel(
    const float* __restrict__ x,
    const float* __restrict__ g, const float* __restrict__ b,
    const float* __restrict__ bm, const float* __restrict__ bvv,
    unsigned short* __restrict__ xa0T_all, int C, int L)
{
    const int p = blockIdx.z & 3;
    const int n = blockIdx.z >> 2;
    const int Lk = c_LKS[p];
    const int lk0 = blockIdx.x * 64;
    if (lk0 >= Lk) return;
    const int r = L / Lk;
    const int ct = blockIdx.y;
    __shared__ float ps[64][65];
    const int tid = threadIdx.x;
    const int c = tid >> 2, q = tid & 3;
    const int cg = p * 128 + ct * 64 + c;
    float inv = g[cg] * rsqrtf(bvv[cg] + EPS);
    float add = b[cg] - bm[cg] * inv;
    const float* xp = x + ((size_t)n * C + cg) * L;
    float rinv = 1.0f / (float)r;
    #pragma unroll
    for (int s = 0; s < 16; ++s) {
        int lk = q * 16 + s;
        const float* base = xp + (size_t)(lk0 + lk) * r;
        float sum = 0.f, mx = -INFINITY;
        for (int j = 0; j < r; j += 2) {
            float2 vv = *(const float2*)&base[j];
            float t0 = fmaf(vv.x, inv, add);
            float t1 = fmaf(vv.y, inv, add);
            sum += t0 + t1;
            mx = fmaxf(mx, fmaxf(t0, t1));
        }
        ps[c][lk] = sum * rinv + mx;
    }
    __syncthreads();
    unsigned short* dst = xa0T_all + c_OFFB[p];
    #pragma unroll
    for (int j = 0; j < 2; ++j) {
        int row = (tid >> 3) + 32 * j;
        int cc0 = (tid & 7) * 8;
        unsigned int w0 = pack2bf(ps[cc0 + 0][row], ps[cc0 + 1][row]);
        unsigned int w1 = pack2bf(ps[cc0 + 2][row], ps[cc0 + 3][row]);
        unsigned int w2 = pack2bf(ps[cc0 + 4][row], ps[cc0 + 5][row]);
        unsigned int w3 = pack2bf(ps[cc0 + 6][row], ps[cc0 + 7][row]);
        *(uint4*)&dst[((size_t)n * Lk + lk0 + row) * 128 + ct * 64 + cc0] =
            make_uint4(w0, w1, w2, w3);
    }
}

// ---------------------------------------------------------------------------
// bf16 MFMA GEMM 128x128, BK=32, counted-vmcnt 2-buffer pipeline,
// phase-conflict-free swizzle (SRC_SEG/RD_SLOT).
// OMODE 1/3 Tn writes go through a unioned-LDS transpose tile [128][128] u16
// (exactly the 32KB staging footprint) with 16B-chunk XOR swizzle
// (chunk' = chunk ^ (row&15): both write and read phases land 2-way/bank),
// then stream 256B-contiguous row segments -> kills the 3.5x scatter write
// amplification measured in R16 (WRITE 88MB vs 25MB ideal on Wq).
// ---------------------------------------------------------------------------
template<int OMODE>
__global__ __launch_bounds__(256) void gemm_bf(
    const unsigned short* __restrict__ A, const unsigned short* __restrict__ BT,
    int M, int K, int Npos, int ldBT, long long strideBT,
    const float* __restrict__ bias, float oscale, int flags,
    const float* __restrict__ g1, const float* __restrict__ b1p,
    const float* __restrict__ m1p, const float* __restrict__ v1p,
    const float* __restrict__ g2, const float* __restrict__ b2p,
    const float* __restrict__ m2p, const float* __restrict__ v2p,
    float* __restrict__ outN, long long strideN,
    const float* __restrict__ resid, long long strideR,
    unsigned short* __restrict__ outT, int ldT, int moff, long long strideT,
    int gKoff)
{
    // unioned LDS: staging As[2][128][32]+Bs[2][128][32] = 32768B
    //            / epilogue transpose tile [128][128] u16 = 32768B
    __shared__ __align__(16) unsigned short smem[16384];
    typedef unsigned short (*TileT)[128][32];
    TileT As = (TileT)smem;
    TileT Bs = (TileT)(smem + 2 * 128 * 32);

    const int tid = threadIdx.x;

    const int gdx = gridDim.x, gdy = gridDim.y;
    const int nwg = gdx * gdy * gridDim.z;
    int bid = blockIdx.x + gdx * (blockIdx.y + gdy * blockIdx.z);
    {
        int q = nwg >> 3, rr = nwg & 7;
        int xcd = bid & 7, idx = bid >> 3;
        bid = (xcd < rr ? xcd * (q + 1) : rr * (q + 1) + (xcd - rr) * q) + idx;
    }
    const int bx = bid % gdx;
    const int by = (bid / gdx) % gdy;
    const int bz = bid / (gdx * gdy);

    const int m0 = by * 128;
    const int p0 = bx * 128;
    const unsigned short* Bn = BT + (size_t)bz * strideBT
                              + (size_t)(m0 >> 7) * gKoff;

    const int wave = tid >> 6;
    const int lane = tid & 63;
    const int qcol = lane & 15;
    const int hi   = lane >> 4;
    const int wr   = wave >> 1;
    const int wc   = wave & 1;
    const int lrow = lane >> 2;
    const int sseg = SRC_SEG(lane);

    const unsigned short* aR0 = A + (size_t)(m0 + wave * 32 + lrow) * K + sseg;
    const unsigned short* aR1 = aR0 + (size_t)16 * K;
    int pr0 = p0 + wave * 32 + lrow;      if (pr0 > Npos - 1) pr0 = Npos - 1;
    int pr1 = p0 + wave * 32 + 16 + lrow; if (pr1 > Npos - 1) pr1 = Npos - 1;
    const unsigned short* bR0 = Bn + (size_t)pr0 * ldBT + sseg;
    const unsigned short* bR1 = Bn + (size_t)pr1 * ldBT + sseg;
    unsigned short* ldsA0 = &As[0][wave * 32][0];
    unsigned short* ldsA1 = &As[0][wave * 32 + 16][0];
    unsigned short* ldsB0 = &Bs[0][wave * 32][0];
    unsigned short* ldsB1 = &Bs[0][wave * 32 + 16][0];
    const int bufStride = 128 * 32;

    auto STAGE = [&](int b, int t) {
        const int ko = t * 32;
        gload_lds16(aR0 + ko, ldsA0 + b * bufStride);
        gload_lds16(aR1 + ko, ldsA1 + b * bufStride);
        gload_lds16(bR0 + ko, ldsB0 + b * bufStride);
        gload_lds16(bR1 + ko, ldsB1 + b * bufStride);
    };

    const int xr = RD_SLOT(qcol, hi);

    f32x4 acc[4][4] = {};
    const int nt = K >> 5;

    STAGE(0, 0);
    STAGE(1, 1);

    auto MFMA_STEP = [&](int b) {
        bf16x8 af[4], bfr[4];
        #pragma unroll
        for (int mi = 0; mi < 4; ++mi)
            af[mi] = *(const bf16x8*)&As[b][wr * 64 + mi * 16 + qcol][xr];
        #pragma unroll
        for (int ni = 0; ni < 4; ++ni)
            bfr[ni] = *(const bf16x8*)&Bs[b][wc * 64 + ni * 16 + qcol][xr];
        #pragma unroll
        for (int mi = 0; mi < 4; ++mi)
            #pragma unroll
            for (int ni = 0; ni < 4; ++ni)
                acc[mi][ni] = __builtin_amdgcn_mfma_f32_16x16x32_bf16(
                    af[mi], bfr[ni], acc[mi][ni], 0, 0, 0);
    };

    int cur = 0;
    for (int t = 0; t < nt - 1; ++t) {
        asm volatile("s_waitcnt vmcnt(4)" ::: "memory");
        __builtin_amdgcn_s_barrier();
        MFMA_STEP(cur);
        __builtin_amdgcn_s_barrier();
        if (t + 2 < nt) STAGE(cur, t + 2);
        cur ^= 1;
    }
    asm volatile("s_waitcnt vmcnt(0)" ::: "memory");
    __builtin_amdgcn_s_barrier();
    MFMA_STEP(cur);

    float* Cn = outN + (size_t)bz * strideN;
    const float* Rn = resid + (size_t)bz * strideR;
    unsigned short* Tn = outT + (size_t)bz * strideT;

    if (OMODE == 1 || OMODE == 3)
        __syncthreads();          // all MFMA LDS reads done; reuse smem

    #pragma unroll
    for (int mi = 0; mi < 4; ++mi) {
        const int mbl = wr * 64 + mi * 16 + hi * 4;   // local m, 0..127
        const int mb = m0 + mbl;
        float4 bv4 = make_float4(0.f, 0.f, 0.f, 0.f);
        if (flags & F_BIAS) bv4 = *(const float4*)&bias[mb];
        float s1[4], t1[4];
        if ((flags & F_DBN) || OMODE == 3) {
            float4 gg = *(const float4*)&g1[mb];
            float4 bb = *(const float4*)&b1p[mb];
            float4 mm = *(const float4*)&m1p[mb];
            float4 vv = *(const float4*)&v1p[mb];
            float gga[4] = {gg.x, gg.y, gg.z, gg.w};
            float bba[4] = {bb.x, bb.y, bb.z, bb.w};
            float mma[4] = {mm.x, mm.y, mm.z, mm.w};
            float vva[4] = {vv.x, vv.y, vv.z, vv.w};
            #pragma unroll
            for (int r2 = 0; r2 < 4; ++r2) {
                float iv = gga[r2] * rsqrtf(vva[r2] + EPS);
                s1[r2] = iv; t1[r2] = bba[r2] - mma[r2] * iv;
            }
        }
        float s2[4], t2[4];
        if (flags & F_DBN) {
            float4 gg = *(const float4*)&g2[mb];
            float4 bb = *(const float4*)&b2p[mb];
            float4 mm = *(const float4*)&m2p[mb];
            float4 vv = *(const float4*)&v2p[mb];
            float gga[4] = {gg.x, gg.y, gg.z, gg.w};
            float bba[4] = {bb.x, bb.y, bb.z, bb.w};
            float mma[4] = {mm.x, mm.y, mm.z, mm.w};
            float vva[4] = {vv.x, vv.y, vv.z, vv.w};
            #pragma unroll
            for (int r2 = 0; r2 < 4; ++r2) {
                float iv = gga[r2] * rsqrtf(vva[r2] + EPS);
                s2[r2] = iv; t2[r2] = bba[r2] - mma[r2] * iv;
            }
        }
        const float ba[4] = {bv4.x, bv4.y, bv4.z, bv4.w};
        #pragma unroll
        for (int ni = 0; ni < 4; ++ni) {
            const int cpl = wc * 64 + ni * 16 + qcol;   // local col, 0..127
            const int cp = p0 + cpl;
            if (cp >= Npos) continue;
            float vals[4];
            #pragma unroll
            for (int r2 = 0; r2 < 4; ++r2) {
                float val = (acc[mi][ni][r2] + ba[r2]) * oscale;
                if (flags & F_DBN) {
                    val = fmaf(val, s1[r2], t1[r2]);
                    val = fmaf(val, s2[r2], t2[r2]);
                }
                if (flags & F_GELU) val = gelu_f(val);
                vals[r2] = val;
            }
            if (OMODE == 0 || OMODE == 3) {
                #pragma unroll
                for (int r2 = 0; r2 < 4; ++r2) {
                    size_t off = (size_t)(mb + r2) * Npos + cp;
                    float v = vals[r2];
                    if (flags & F_RESID) v += Rn[off];
                    Cn[off] = v;
                    vals[r2] = v;
                }
            }
            if (OMODE == 1) {
                const int ch = ((mbl >> 3) ^ (cpl & 15)) * 8;
                *(uint2*)&smem[cpl * 128 + ch + (mbl & 7)] =
                    make_uint2(pack2bf(vals[0], vals[1]), pack2bf(vals[2], vals[3]));
            }
            if (OMODE == 2) {
                #pragma unroll
                for (int r2 = 0; r2 < 4; ++r2)
                    Tn[(size_t)(mb + r2) * Npos + cp] =
                        __builtin_bit_cast(unsigned short, (__bf16)vals[r2]);
            }
            if (OMODE == 3) {
                float a0 = fmaf(vals[0], s1[0], t1[0]);
                float a1 = fmaf(vals[1], s1[1], t1[1]);
                float a2 = fmaf(vals[2], s1[2], t1[2]);
                float a3 = fmaf(vals[3], s1[3], t1[3]);
                const int ch = ((mbl >> 3) ^ (cpl & 15)) * 8;
                *(uint2*)&smem[cpl * 128 + ch + (mbl & 7)] =
                    make_uint2(pack2bf(a0, a1), pack2bf(a2, a3));
            }
        }
    }

    if (OMODE == 1 || OMODE == 3) {
        __syncthreads();
        // stream out: 128 rows x 256B, 16 lanes x 16B contiguous per row
        #pragma unroll
        for (int pass = 0; pass < 8; ++pass) {
            const int row = pass * 16 + (tid >> 4);
            const int c = tid & 15;
            uint4 v = *(const uint4*)&smem[row * 128 + ((c ^ (row & 15)) * 8)];
            *(uint4*)&Tn[(size_t)(p0 + row) * ldT + moff + m0 + c * 8] = v;
        }
    }
}

// ---------------------------------------------------------------------------
// bf16 MFMA FFN GEMM: 128x256 tile, BK=32, 3-BUFFER counted-vmcnt ring
// (R15-proven). OMODE 1: LDS-staged transpose epilogue (R16-proven).
// OMODE: 0 = f32 natural out (+resid);  1 = bf16 transposed out [cp][ldT].
// ---------------------------------------------------------------------------
template<int OMODE, int FLAGS>
__global__ __launch_bounds__(512, 1) void gemm_ffn(
    const unsigned short* __restrict__ A, const unsigned short* __restrict__ BT,
    int K, int Npos, int ldBT, long long strideBT,
    const float* __restrict__ bias,
    float* __restrict__ outN, long long strideN,
    const float* __restrict__ resid, long long strideR,
    unsigned short* __restrict__ outT, int ldT, long long strideT)
{
    __shared__ __align__(16) unsigned short smem[3 * 128 * 32 + 3 * 256 * 32];
    typedef unsigned short (*AsT)[128][32];
    typedef unsigned short (*BsT)[256][32];
    AsT As = (AsT)smem;
    BsT Bs = (BsT)(smem + 3 * 128 * 32);

    const int tid = threadIdx.x;

    const int gdx = gridDim.x, gdy = gridDim.y;
    const int nwg = gdx * gdy * gridDim.z;
    int bid = blockIdx.x + gdx * (blockIdx.y + gdy * blockIdx.z);
    {
        int q = nwg >> 3, rr = nwg & 7;
        int xcd = bid & 7, idx = bid >> 3;
        bid = (xcd < rr ? xcd * (q + 1) : rr * (q + 1) + (xcd - rr) * q) + idx;
    }
    const int bx = bid % gdx;
    const int by = (bid / gdx) % gdy;
    const int bz = bid / (gdx * gdy);

    const int m0 = by * 128;
    const int p0 = bx * 256;
    const unsigned short* Bn = BT + (size_t)bz * strideBT;

    const int wave = tid >> 6;
    const int lane = tid & 63;
    const int qcol = lane & 15;
    const int hi   = lane >> 4;
    const int wr   = wave >> 2;
    const int wc   = wave & 3;

    const int lrow4 = lane >> 2;
    const int sseg  = SRC_SEG(lane);

    const unsigned short* aS0 = A + (size_t)(m0 + wave * 16 + lrow4) * K + sseg;
    const unsigned short* bS0 = Bn + (size_t)(p0 + wave * 32 + lrow4) * ldBT + sseg;
    const unsigned short* bS1 = bS0 + (size_t)16 * ldBT;
    unsigned short* ldsA0 = &As[0][wave * 16][0];
    unsigned short* ldsB0 = &Bs[0][wave * 32][0];
    unsigned short* ldsB1 = &Bs[0][wave * 32 + 16][0];
    const int aStride = 128 * 32;
    const int bStride = 256 * 32;

    auto STAGE = [&](int b, int t) {
        const int ko = t * 32;
        gload_lds16(aS0 + ko, ldsA0 + b * aStride);
        gload_lds16(bS0 + ko, ldsB0 + b * bStride);
        gload_lds16(bS1 + ko, ldsB1 + b * bStride);
    };

    const int xr = RD_SLOT(qcol, hi);

    f32x4 acc[4][4] = {};
    const int nt = K >> 5;

    STAGE(0, 0);
    STAGE(1, 1);
    STAGE(2, 2);

    auto MFMA_STEP = [&](int b) {
        bf16x8 af[4], bfr[4];
        #pragma unroll
        for (int mi = 0; mi < 4; ++mi)
            af[mi] = *(const bf16x8*)&As[b][wr * 64 + mi * 16 + qcol][xr];
        #pragma unroll
        for (int ni = 0; ni < 4; ++ni)
            bfr[ni] = *(const bf16x8*)&Bs[b][wc * 64 + ni * 16 + qcol][xr];
        #pragma unroll
        for (int mi = 0; mi < 4; ++mi)
            #pragma unroll
            for (int ni = 0; ni < 4; ++ni)
                acc[mi][ni] = __builtin_amdgcn_mfma_f32_16x16x32_bf16(
                    af[mi], bfr[ni], acc[mi][ni], 0, 0, 0);
    };

    int cur = 0;
    for (int t = 0; t < nt; ++t) {
        const int rem = nt - t;
        if (rem >= 3)      { asm volatile("s_waitcnt vmcnt(6)" ::: "memory"); }
        else if (rem == 2) { asm volatile("s_waitcnt vmcnt(3)" ::: "memory"); }
        else               { asm volatile("s_waitcnt vmcnt(0)" ::: "memory"); }
        __builtin_amdgcn_s_barrier();
        __builtin_amdgcn_s_setprio(1);
        MFMA_STEP(cur);
        __builtin_amdgcn_s_setprio(0);
        __builtin_amdgcn_s_barrier();
        if (t + 3 < nt) STAGE(cur, t + 3);
        cur = (cur == 2) ? 0 : cur + 1;
    }

    float* Cn = outN + (size_t)bz * strideN;
    const float* Rn = resid + (size_t)bz * strideR;
    unsigned short* Tn = outT + (size_t)bz * strideT;

    if (OMODE == 1) {
        __syncthreads();
        #pragma unroll
        for (int mi = 0; mi < 4; ++mi) {
            const int mbl = wr * 64 + mi * 16 + hi * 4;
            const int mbg = m0 + mbl;
            float ba[4] = {0.f, 0.f, 0.f, 0.f};
            if (FLAGS & F_BIAS) {
                float4 bv4 = *(const float4*)&bias[mbg];
                ba[0] = bv4.x; ba[1] = bv4.y; ba[2] = bv4.z; ba[3] = bv4.w;
            }
            #pragma unroll
            for (int ni = 0; ni < 4; ++ni) {
                const int cpl = wc * 64 + ni * 16 + qcol;
                float vals[4];
                #pragma unroll
                for (int r2 = 0; r2 < 4; ++r2) {
                    float val = acc[mi][ni][r2] + ba[r2];
                    if (FLAGS & F_GELU) val = gelu_f(val);
                    vals[r2] = val;
                }
                *(uint2*)&smem[cpl * 136 + mbl] =
                    make_uint2(pack2bf(vals[0], vals[1]), pack2bf(vals[2], vals[3]));
            }
        }
        __syncthreads();
        #pragma unroll
        for (int pass = 0; pass < 8; ++pass) {
            const int row = pass * 32 + (tid >> 4);
            const int c16 = (tid & 15) * 8;
            uint4 v = *(const uint4*)&smem[row * 136 + c16];
            *(uint4*)&Tn[(size_t)(p0 + row) * ldT + m0 + c16] = v;
        }
    } else {
        #pragma unroll
        for (int mi = 0; mi < 4; ++mi) {
            const int mb = m0 + wr * 64 + mi * 16 + hi * 4;
            float ba[4] = {0.f, 0.f, 0.f, 0.f};
            if (FLAGS & F_BIAS) {
                float4 bv4 = *(const float4*)&bias[mb];
                ba[0] = bv4.x; ba[1] = bv4.y; ba[2] = bv4.z; ba[3] = bv4.w;
            }
            #pragma unroll
            for (int ni = 0; ni < 4; ++ni) {
                const int cp = p0 + wc * 64 + ni * 16 + qcol;
                float vals[4];
                #pragma unroll
                for (int r2 = 0; r2 < 4; ++r2) {
                    float val = acc[mi][ni][r2] + ba[r2];
                    if (FLAGS & F_GELU) val = gelu_f(val);
                    vals[r2] = val;
                }
                #pragma unroll
                for (int r2 = 0; r2 < 4; ++r2) {
                    size_t off = (size_t)(mb + r2) * Npos + cp;
                    float v = vals[r2];
                    if (FLAGS & F_RESID) v += Rn[off];
                    Cn[off] = v;
                }
            }
        }
    }
}

// ---------------------------------------------------------------------------
// Grouped per-path GEMM (K=128, M=128 per path), all 4 paths in one dispatch.
// ---------------------------------------------------------------------------
template<int MODE>
__global__ __launch_bounds__(256) void gemm_path(
    const unsigned short* __restrict__ A0, const unsigned short* __restrict__ A1,
    const unsigned short* __restrict__ Bsrc,
    const float* __restrict__ bias0, const float* __restrict__ bias1,
    const float* __restrict__ agg, const float* __restrict__ agb,
    const float* __restrict__ agm, const float* __restrict__ agv,
    const float* __restrict__ ang, const float* __restrict__ anb,
    const float* __restrict__ anm, const float* __restrict__ anv,
    unsigned short* __restrict__ out0, unsigned short* __restrict__ out1)
{
    __shared__ __align__(16) unsigned short As[2][128][32];
    __shared__ __align__(16) unsigned short Bs[2][128][32];

    const int tid = threadIdx.x;
    const int gdx = gridDim.x, gdy = gridDim.y;
    const int nwg = gdx * gdy * gridDim.z;
    int bid = blockIdx.x + gdx * (blockIdx.y + gdy * blockIdx.z);
    {
        int q = nwg >> 3, rr = nwg & 7;
        int xcd = bid & 7, idx = bid >> 3;
        bid = (xcd < rr ? xcd * (q + 1) : rr * (q + 1) + (xcd - rr) * q) + idx;
    }
    const int bx = bid % gdx;
    const int by = (bid / gdx) % gdy;
    const int bz = bid / (gdx * gdy);

    int p, px;
    if      (bx < 12) { p = 0; px = bx; }
    else if (bx < 18) { p = 1; px = bx - 12; }
    else if (bx < 21) { p = 2; px = bx - 18; }
    else              { p = 3; px = bx - 21; }
    const int Lk = c_LKS[p];
    const int offb = c_OFFB[p];
    const int c0 = p * 128;
    const int p0 = px * 128;
    const int K = 128;

    const unsigned short* A = (MODE == 1 && by == 1 ? A1 : A0) + p * 16384;
    const unsigned short* Bn = Bsrc + offb + (size_t)bz * Lk * 128;

    const int wave = tid >> 6;
    const int lane = tid & 63;
    const int qcol = lane & 15;
    const int hi   = lane >> 4;
    const int wr   = wave >> 1;
    const int wc   = wave & 1;
    const int lrow = lane >> 2;
    const int sseg = SRC_SEG(lane);

    const unsigned short* aR0 = A + (size_t)(wave * 32 + lrow) * K + sseg;
    const unsigned short* aR1 = aR0 + (size_t)16 * K;
    int pr0 = p0 + wave * 32 + lrow;      if (pr0 > Lk - 1) pr0 = Lk - 1;
    int pr1 = p0 + wave * 32 + 16 + lrow; if (pr1 > Lk - 1) pr1 = Lk - 1;
    const unsigned short* bR0 = Bn + (size_t)pr0 * 128 + sseg;
    const unsigned short* bR1 = Bn + (size_t)pr1 * 128 + sseg;
    unsigned short* ldsA0 = &As[0][wave * 32][0];
    unsigned short* ldsA1 = &As[0][wave * 32 + 16][0];
    unsigned short* ldsB0 = &Bs[0][wave * 32][0];
    unsigned short* ldsB1 = &Bs[0][wave * 32 + 16][0];
    const int bufStride = 128 * 32;

    auto STAGE = [&](int b, int t) {
        const int ko = t * 32;
        gload_lds16(aR0 + ko, ldsA0 + b * bufStride);
        gload_lds16(aR1 + ko, ldsA1 + b * bufStride);
        gload_lds16(bR0 + ko, ldsB0 + b * bufStride);
        gload_lds16(bR1 + ko, ldsB1 + b * bufStride);
    };

    const int xr = RD_SLOT(qcol, hi);

    f32x4 acc[4][4] = {};
    STAGE(0, 0);
    STAGE(1, 1);

    auto MFMA_STEP = [&](int b) {
        bf16x8 af[4], bfr[4];
        #pragma unroll
        for (int mi = 0; mi < 4; ++mi)
            af[mi] = *(const bf16x8*)&As[b][wr * 64 + mi * 16 + qcol][xr];
        #pragma unroll
        for (int ni = 0; ni < 4; ++ni)
            bfr[ni] = *(const bf16x8*)&Bs[b][wc * 64 + ni * 16 + qcol][xr];
        #pragma unroll
        for (int mi = 0; mi < 4; ++mi)
            #pragma unroll
            for (int ni = 0; ni < 4; ++ni)
                acc[mi][ni] = __builtin_amdgcn_mfma_f32_16x16x32_bf16(
                    af[mi], bfr[ni], acc[mi][ni], 0, 0, 0);
    };

    int cur = 0;
    const int nt = 4;
    for (int t = 0; t < nt - 1; ++t) {
        asm volatile("s_waitcnt vmcnt(4)" ::: "memory");
        __builtin_amdgcn_s_barrier();
        MFMA_STEP(cur);
        __builtin_amdgcn_s_barrier();
        if (t + 2 < nt) STAGE(cur, t + 2);
        cur ^= 1;
    }
    asm volatile("s_waitcnt vmcnt(0)" ::: "memory");
    __builtin_amdgcn_s_barrier();
    MFMA_STEP(cur);

    const bool isV = (MODE == 1 && by == 1);
    unsigned short* Tn = (isV ? out1 : out0) + offb + (size_t)bz * Lk * 128;
    const float* bias = (MODE == 0) ? nullptr : (by == 0 ? bias0 : bias1);

    #pragma unroll
    for (int mi = 0; mi < 4; ++mi) {
        const int mb = wr * 64 + mi * 16 + hi * 4;
        float ba[4] = {0.f, 0.f, 0.f, 0.f};
        if (MODE == 1) {
            float4 bv4 = *(const float4*)&bias[c0 + mb];
            ba[0] = bv4.x; ba[1] = bv4.y; ba[2] = bv4.z; ba[3] = bv4.w;
        }
        float s1[4], t1[4], s2[4], t2[4];
        if (MODE == 0) {
            #pragma unroll
            for (int r2 = 0; r2 < 4; ++r2) {
                int gm = c0 + mb + r2;
                float i1 = agg[gm] * rsqrtf(agv[gm] + EPS);
                s1[r2] = i1; t1[r2] = agb[gm] - agm[gm] * i1;
                float i2 = ang[gm] * rsqrtf(anv[gm] + EPS);
                s2[r2] = i2; t2[r2] = anb[gm] - anm[gm] * i2;
            }
        }
        #pragma unroll
        for (int ni = 0; ni < 4; ++ni) {
            const int cp = p0 + wc * 64 + ni * 16 + qcol;
            if (cp >= Lk) continue;
            float vals[4];
            #pragma unroll
            for (int r2 = 0; r2 < 4; ++r2) {
                float val = acc[mi][ni][r2] + ba[r2];
                if (MODE == 0) {
                    val = fmaf(val, s1[r2], t1[r2]);
                    val = fmaf(val, s2[r2], t2[r2]);
                }
                vals[r2] = val;
            }
            if (!isV) {
                *(uint2*)&Tn[(size_t)cp * 128 + mb] =
                    make_uint2(pack2bf(vals[0], vals[1]), pack2bf(vals[2], vals[3]));
            } else {
                #pragma unroll
                for (int r2 = 0; r2 < 4; ++r2)
                    Tn[(size_t)(mb + r2) * Lk + cp] =
                        __builtin_bit_cast(unsigned short, (__bf16)vals[r2]);
            }
        }
    }
}

// ---------------------------------------------------------------------------
// Flash attention, all paths; K/V staged in block-shared LDS (counted-vmcnt
// 2-buffer pipeline, 128B-row XOR swizzle). grid (48, N*2, 4).
// ---------------------------------------------------------------------------
__global__ __launch_bounds__(256) void attn_bf_all_kernel(
    const unsigned short* __restrict__ qT, const unsigned short* __restrict__ kT_all,
    const unsigned short* __restrict__ vN_all, unsigned short* __restrict__ obT,
    int L)
{
    const int p = blockIdx.z;
    const int Lk = c_LKS[p];
    const int offb = c_OFFB[p];
    const int l0 = blockIdx.x * 64;
    const int nh = blockIdx.y;
    const int n = nh >> 1, h = nh & 1;
    const unsigned short* qn = qT + (size_t)n * L * 512 + p * 128 + h * 64;
    const unsigned short* kn = kT_all + offb + (size_t)n * Lk * 128 + h * 64;
    const unsigned short* vn = vN_all + offb + ((size_t)n * 128 + h * 64) * Lk;
    unsigned short*       on = obT + (size_t)n * L * 512 + p * 128 + h * 64;

    __shared__ __align__(16) unsigned short Ks[2][64][64];
    __shared__ __align__(16) unsigned short Vs[2][64][64];
    __shared__ __align__(16) unsigned short Ps[4][16][72];

    const int tid = threadIdx.x;
    const int wave = tid >> 6;
    const int lane = tid & 63;
    const int qcol = lane & 15;
    const int hi   = lane >> 4;
    const int ql   = wave * 16 + qcol;

    const int srow = lane >> 3;
    const int sxor = (lane & 7) ^ srow;
    const unsigned short* kS0 = kn + (size_t)(wave * 16 + srow) * 128 + sxor * 8;
    const unsigned short* kS1 = kn + (size_t)(wave * 16 + 8 + srow) * 128 + sxor * 8;
    const unsigned short* vS0 = vn + (size_t)(wave * 16 + srow) * Lk + sxor * 8;
    const unsigned short* vS1 = vn + (size_t)(wave * 16 + 8 + srow) * Lk + sxor * 8;
    unsigned short* ldsK0 = &Ks[0][wave * 16][0];
    unsigned short* ldsK1 = &Ks[0][wave * 16 + 8][0];
    unsigned short* ldsV0 = &Vs[0][wave * 16][0];
    unsigned short* ldsV1 = &Vs[0][wave * 16 + 8][0];
    const int bufStride = 64 * 64;

    auto STAGE = [&](int b, int t) {
        const int mc = t * 64;
        gload_lds16(kS0 + (size_t)mc * 128, ldsK0 + b * bufStride);
        gload_lds16(kS1 + (size_t)mc * 128, ldsK1 + b * bufStride);
        gload_lds16(vS0 + mc, ldsV0 + b * bufStride);
        gload_lds16(vS1 + mc, ldsV1 + b * bufStride);
    };

    const int x0 = (hi ^ (qcol & 7)) * 8;
    const int x1 = x0 ^ 32;

    bf16x8 qf0 = *(const bf16x8*)&qn[(size_t)(l0 + ql) * 512 + hi * 8];
    bf16x8 qf1 = *(const bf16x8*)&qn[(size_t)(l0 + ql) * 512 + 32 + hi * 8];

    f32x4 o_acc[4] = {};
    float mrow = -INFINITY, lrow = 0.f;
    const int nt = Lk >> 6;

    STAGE(0, 0);
    STAGE(1, 1);

    auto COMPUTE = [&](int b) {
        f32x4 sacc[4];
        #pragma unroll
        for (int kt = 0; kt < 4; ++kt) {
            bf16x8 k0 = *(const bf16x8*)&Ks[b][kt * 16 + qcol][x0];
            bf16x8 k1 = *(const bf16x8*)&Ks[b][kt * 16 + qcol][x1];
            f32x4 a = {};
            a = __builtin_amdgcn_mfma_f32_16x16x32_bf16(k0, qf0, a, 0, 0, 0);
            a = __builtin_amdgcn_mfma_f32_16x16x32_bf16(k1, qf1, a, 0, 0, 0);
            sacc[kt] = a;
        }
        float m0 = fmaxf(fmaxf(sacc[0][0], sacc[0][1]), fmaxf(sacc[0][2], sacc[0][3]));
        float m1 = fmaxf(fmaxf(sacc[1][0], sacc[1][1]), fmaxf(sacc[1][2], sacc[1][3]));
        float m2 = fmaxf(fmaxf(sacc[2][0], sacc[2][1]), fmaxf(sacc[2][2], sacc[2][3]));
        float m3 = fmaxf(fmaxf(sacc[3][0], sacc[3][1]), fmaxf(sacc[3][2], sacc[3][3]));
        float cm = fmaxf(fmaxf(m0, m1), fmaxf(m2, m3));
        cm = fmaxf(cm, __shfl_xor(cm, 16));
        cm = fmaxf(cm, __shfl_xor(cm, 32));
        float nm = fmaxf(mrow, cm);
        float alpha = __expf(mrow - nm);
        float csum = 0.f;
        unsigned int pw[4][2];
        #pragma unroll
        for (int kt = 0; kt < 4; ++kt) {
            float p0 = __expf(sacc[kt][0] - nm);
            float p1 = __expf(sacc[kt][1] - nm);
            float p2 = __expf(sacc[kt][2] - nm);
            float p3 = __expf(sacc[kt][3] - nm);
            csum += (p0 + p1) + (p2 + p3);
            pw[kt][0] = pack2bf(p0, p1);
            pw[kt][1] = pack2bf(p2, p3);
        }
        csum += __shfl_xor(csum, 16);
        csum += __shfl_xor(csum, 32);
        lrow = lrow * alpha + csum;
        mrow = nm;

        #pragma unroll
        for (int kt = 0; kt < 4; ++kt)
            *(uint2*)&Ps[wave][qcol][kt * 16 + hi * 4] =
                make_uint2(pw[kt][0], pw[kt][1]);

        #pragma unroll
        for (int et = 0; et < 4; ++et)
            #pragma unroll
            for (int r2 = 0; r2 < 4; ++r2) o_acc[et][r2] *= alpha;

        bf16x8 pf0 = *(const bf16x8*)&Ps[wave][qcol][hi * 8];
        bf16x8 pf1 = *(const bf16x8*)&Ps[wave][qcol][hi * 8 + 32];
        #pragma unroll
        for (int et = 0; et < 4; ++et) {
            bf16x8 v0 = *(const bf16x8*)&Vs[b][et * 16 + qcol][x0];
            bf16x8 v1 = *(const bf16x8*)&Vs[b][et * 16 + qcol][x1];
            o_acc[et] = __builtin_amdgcn_mfma_f32_16x16x32_bf16(v0, pf0, o_acc[et], 0, 0, 0);
            o_acc[et] = __builtin_amdgcn_mfma_f32_16x16x32_bf16(v1, pf1, o_acc[et], 0, 0, 0);
        }
    };

    int cur = 0;
    for (int t = 0; t < nt - 1; ++t) {
        asm volatile("s_waitcnt vmcnt(4)" ::: "memory");
        __builtin_amdgcn_s_barrier();
        COMPUTE(cur);
        __builtin_amdgcn_s_barrier();
        if (t + 2 < nt) STAGE(cur, t + 2);
        cur ^= 1;
    }
    asm volatile("s_waitcnt vmcnt(0)" ::: "memory");
    __builtin_amdgcn_s_barrier();
    COMPUTE(cur);

    float invl = 1.f / lrow;
    #pragma unroll
    for (int et = 0; et < 4; ++et) {
        float a0 = o_acc[et][0] * invl, a1 = o_acc[et][1] * invl;
        float a2 = o_acc[et][2] * invl, a3 = o_acc[et][3] * invl;
        *(uint2*)&on[(size_t)(l0 + ql) * 512 + et * 16 + hi * 4] =
            make_uint2(pack2bf(a0, a1), pack2bf(a2, a3));
    }
}

// ---------------------------------------------------------------------------
extern "C" void kernel_launch(void* const* d_in, const int* in_sizes, int n_in,
                              void* d_out, int out_size, void* d_ws, size_t ws_size,
                              hipStream_t stream)
{
    const float* x   = (const float*)d_in[0];
    const float* n1g = (const float*)d_in[1];
    const float* n1b = (const float*)d_in[2];
    const float* n1m = (const float*)d_in[3];
    const float* n1v = (const float*)d_in[4];
    const float* n2g = (const float*)d_in[5];
    const float* n2b = (const float*)d_in[6];
    const float* n2m = (const float*)d_in[7];
    const float* n2v = (const float*)d_in[8];
    const float* Wq  = (const float*)d_in[9];
    const float* Wk  = (const float*)d_in[10];
    const float* Wv  = (const float*)d_in[11];
    const float* Wo  = (const float*)d_in[12];
    const float* Wp  = (const float*)d_in[13];
    const float* bq  = (const float*)d_in[14];
    const float* bk  = (const float*)d_in[15];
    const float* bv  = (const float*)d_in[16];
    const float* bo  = (const float*)d_in[17];
    const float* agg = (const float*)d_in[18];
    const float* agb = (const float*)d_in[19];
    const float* agm = (const float*)d_in[20];
    const float* agv = (const float*)d_in[21];
    const float* ang = (const float*)d_in[22];
    const float* anb = (const float*)d_in[23];
    const float* anm = (const float*)d_in[24];
    const float* anv = (const float*)d_in[25];
    const float* W1  = (const float*)d_in[26];
    const float* b1  = (const float*)d_in[27];
    const float* W2  = (const float*)d_in[28];
    const float* b2  = (const float*)d_in[29];

    float* out = (float*)d_out;
    unsigned short* wsb = (unsigned short*)d_ws;

    const int N = 8, Cc = 512, L = 3072, FF = 2048;
    const int WSZ = 65536, FSZ = 1048576;
    const size_t PATHBUF = 2949120;

    unsigned short* wbf      = wsb;
    unsigned short* hT       = wbf      + 5 * WSZ + 2 * FSZ;
    unsigned short* h2T      = hT;                              // alias
    unsigned short* obT      = hT       + (size_t)N * L * Cc;
    unsigned short* xa0T_all = obT      + (size_t)N * L * 512;
    unsigned short* xabT_all = xa0T_all + PATHBUF;
    unsigned short* kT_all   = xabT_all + PATHBUF;
    unsigned short* vN_all   = kT_all   + PATHBUF;
    unsigned short* m1T      = vN_all   + PATHBUF;
    unsigned short* qTall    = m1T;

    const unsigned short* WqB = wbf;
    const unsigned short* WkB = wbf + WSZ;
    const unsigned short* WvB = wbf + 2 * WSZ;
    const unsigned short* WoB = wbf + 3 * WSZ;
    const unsigned short* WpB = wbf + 4 * WSZ;
    const unsigned short* W1B = wbf + 5 * WSZ;
    const unsigned short* W2B = wbf + 5 * WSZ + FSZ;

    const float* nul = nullptr;
    float* nulf = nullptr;
    unsigned short* nulu = nullptr;

    {
        long long tot4 = (5LL * WSZ + 2LL * FSZ) / 4;
        wcvt_kernel<<<dim3((unsigned)((tot4 + 255) / 256)), dim3(256), 0, stream>>>(
            Wq, Wk, Wv, Wo, Wp, W1, W2, wbf);
    }
    bn_transpose_kernel<<<dim3(L / 64, Cc / 64, N), dim3(256), 0, stream>>>(
        x, n1g, n1b, n1m, n1v, hT, Cc, L);

    pool_bn_all_kernel<<<dim3(24, 2, N * 4), dim3(256), 0, stream>>>(
        x, n1g, n1b, n1m, n1v, xa0T_all, Cc, L);

    // grouped Q: all paths, block-diag Wq (128^2 kernel, K=128)
    gemm_bf<1><<<dim3(L / 128, 4, N), dim3(256), 0, stream>>>(
        WqB, hT, 512, 128, L, Cc, (long long)L * Cc,
        bq, 0.125f, F_BIAS,
        nul, nul, nul, nul, nul, nul, nul, nul,
        nulf, 0, nul, 0, qTall, 512, 0, (long long)L * 512, 128);

    // grouped Wp (all paths)
    gemm_path<0><<<dim3(23, 1, N), dim3(256), 0, stream>>>(
        WpB, nulu, xa0T_all, nul, nul,
        agg, agb, agm, agv, ang, anb, anm, anv,
        xabT_all, nulu);

    // grouped Wk+Wv (all paths)
    gemm_path<1><<<dim3(23, 2, N), dim3(256), 0, stream>>>(
        WkB, WvB, xabT_all, bk, bv,
        nul, nul, nul, nul, nul, nul, nul, nul,
        kT_all, vN_all);

    // all-path attention
    attn_bf_all_kernel<<<dim3(L / 64, N * 2, 4), dim3(256), 0, stream>>>(
        qTall, kT_all, vN_all, obT, L);

    // grouped Wo: out = x + Wo @ o + bo (f32), h2T aux = bf16(bn2(out))
    gemm_bf<3><<<dim3(L / 128, 4, N), dim3(256), 0, stream>>>(
        WoB, obT, 512, 128, L, 512, (long long)L * 512,
        bo, 1.f, F_BIAS | F_RESID,
        n2g, n2b, n2m, n2v,
        nul, nul, nul, nul,
        out, (long long)Cc * L,
        x, (long long)Cc * L,
        h2T, Cc, 0, (long long)L * Cc, 128);

    // FFN: both on 128x256 / 3-buffer deep pipeline (2 blocks/CU)
    // m1T = bf16(gelu(W1 @ h2 + b1))^T   (LDS-transposed coalesced epilogue)
    gemm_ffn<1, F_BIAS | F_GELU><<<dim3(L / 256, FF / 128, N), dim3(512), 0, stream>>>(
        W1B, h2T, Cc, L, Cc, (long long)L * Cc,
        b1,
        nulf, 0, nul, 0,
        m1T, FF, (long long)L * FF);

    // out += W2 @ m1 + b2
    gemm_ffn<0, F_BIAS | F_RESID><<<dim3(L / 256, Cc / 128, N), dim3(512), 0, stream>>>(
        W2B, m1T, FF, L, FF, (long long)L * FF,
        b2,
        out, (long long)Cc * L, out, (long long)Cc * L,
        nulu, 0, 0);
}